// Round 17
// baseline (1100.724 us; speedup 1.0000x reference)
//
#include <hip/hip_runtime.h>
#include <hip/hip_bf16.h>

// Shapes (fixed): B=4, L=64, E=8, Q=16, K=32, H=512, NH=8, HD=64
// R17: kill the proj latency wall with TLP + zero-LDS GEMMs.
// Diagnosis R16: K/V proj 115us each; wt loads from L2 serialize (VGPR=64, no
// prefetch depth, 2 blocks/CU from 66KB LDS). Fix: 16-row blocks, A-fragments
// loaded DIRECTLY from global (32B contiguous per lane, convert in-reg), no LDS,
// no barriers, acc=16 VGPR -> ~55 VGPR -> 8 waves/SIMD, 32 waves/CU.
// Same for out_gemm (A bf16 in ws -> single short8v per fragment).
// attn_mid + prep_w verbatim from R16 (passed, absmax 9.77e-4).
// ws (proven >= 169,869,312): wt@0 2MB | qp@2M (x aliases) | kp@35.65M | vpT@102.76M.

#define THREADS 512

typedef __attribute__((ext_vector_type(8))) short short8v;
typedef __attribute__((ext_vector_type(4))) short short4v;
typedef __attribute__((ext_vector_type(4))) float f32x4;

__device__ __forceinline__ short bf16b(float f) {
  __hip_bfloat16 h = __float2bfloat16(f);
  return *reinterpret_cast<short*>(&h);
}

// ---- W prep: wt[mat][n][k] = bf16(W[k][n]) ----
__global__ __launch_bounds__(256) void prep_w(const float* __restrict__ Wq,
                                              const float* __restrict__ Wk,
                                              const float* __restrict__ Wv,
                                              const float* __restrict__ Wo,
                                              short* __restrict__ wt) {
  __shared__ float tile[32][33];
  const int mat = blockIdx.x >> 8;
  const int tix = blockIdx.x & 255;
  const int n0 = (tix & 15) * 32, k0 = (tix >> 4) * 32;
  const float* W = (mat == 0) ? Wq : (mat == 1) ? Wk : (mat == 2) ? Wv : Wo;
  const int tx = threadIdx.x & 31, ty = threadIdx.x >> 5;
#pragma unroll
  for (int i = 0; i < 4; ++i)
    tile[ty + 8 * i][tx] = W[(size_t)(k0 + ty + 8 * i) * 512 + n0 + tx];
  __syncthreads();
#pragma unroll
  for (int i = 0; i < 4; ++i) {
    int n = ty + 8 * i, k = tx;
    wt[((size_t)(mat * 512 + n0 + n) << 9) + k0 + k] = bf16b(tile[k][n]);
  }
}

// ---- projection GEMM v3: 16 rows x 512 cols per block, NO LDS, NO barriers ----
// MAT 0=Q(row-major, x0.125), 1=K(row-major), 2=V(transposed vpT[ble][n][key])
template <int MAT>
__global__ __launch_bounds__(THREADS, 8) void proj_v3(const float* __restrict__ A,
                                                      const float* __restrict__ bvec,
                                                      const short* __restrict__ wt,
                                                      short* __restrict__ C) {
  const int t = threadIdx.x, lane = t & 63, w = t >> 6;
  const int lr = lane & 15, lo = lane >> 4;
  const int nw = w * 64;
  const int R0 = blockIdx.x * 16;

  const float* arow = A + (size_t)(R0 + lr) * 512;
  f32x4 acc[4] = {};
#pragma unroll
  for (int ks = 0; ks < 16; ++ks) {
    float4 af0 = *(const float4*)&arow[ks * 32 + lo * 8];
    float4 af1 = *(const float4*)&arow[ks * 32 + lo * 8 + 4];
    short8v a = {bf16b(af0.x), bf16b(af0.y), bf16b(af0.z), bf16b(af0.w),
                 bf16b(af1.x), bf16b(af1.y), bf16b(af1.z), bf16b(af1.w)};
#pragma unroll
    for (int nt = 0; nt < 4; ++nt) {
      short8v b = *(const short8v*)(wt + (((size_t)(MAT * 512 + nw + nt * 16 + lr)) << 9) +
                                    ks * 32 + lo * 8);
      acc[nt] = __builtin_amdgcn_mfma_f32_16x16x32_bf16(a, b, acc[nt], 0, 0, 0);
    }
  }

#pragma unroll
  for (int nt = 0; nt < 4; ++nt) {
    int n = nw + nt * 16 + lr;
    float bb = bvec[n];
    if (MAT == 2) {
      int rl0 = lo * 4;
      int ble2 = (R0 + rl0) >> 5, key0 = (R0 + rl0) & 31;
      short4v s4 = {bf16b(acc[nt][0] + bb), bf16b(acc[nt][1] + bb),
                    bf16b(acc[nt][2] + bb), bf16b(acc[nt][3] + bb)};
      *(short4v*)(C + (size_t)ble2 * 16384 + n * 32 + key0) = s4;
    } else {
#pragma unroll
      for (int r = 0; r < 4; ++r) {
        int rl = lo * 4 + r;
        float v = acc[nt][r] + bb;
        if (MAT == 0) {
          int ble2 = (R0 + rl) >> 4, q = (R0 + rl) & 15;
          C[(size_t)ble2 * 8192 + q * 512 + n] = bf16b(v * 0.125f);
        } else {
          int ble2 = (R0 + rl) >> 5, key = (R0 + rl) & 31;
          C[(size_t)ble2 * 16384 + key * 512 + n] = bf16b(v);
        }
      }
    }
  }
}

// ---- attention mid: scores + softmax + top + PV -> x (bf16, aliases qp) ----
__global__ __launch_bounds__(THREADS, 4) void attn_mid(
    const short* __restrict__ qp, const short* __restrict__ kp, const short* __restrict__ vpT,
    const float* __restrict__ bias, short* __restrict__ xbuf, float* __restrict__ top) {
  extern __shared__ char smem[];  // p[8][16][40]s @0 (10240B) ; x[16][520]s @10240
  const int t = threadIdx.x, lane = t & 63, w = t >> 6;
  const int ble = blockIdx.x, e = ble & 7, bl = ble >> 3;
  const int lr = lane & 15, lo = lane >> 4;
  const int nw = w * 64;

  const short* qb = qp + (size_t)ble * 8192;
  const short* kb = kp + (size_t)ble * 16384;
  const short* vb = vpT + (size_t)ble * 16384;

  const float* brow = bias + (size_t)ble * 512;
  float bias8[8];
#pragma unroll
  for (int kt = 0; kt < 2; ++kt)
#pragma unroll
    for (int r = 0; r < 4; ++r)
      bias8[kt * 4 + r] = brow[(lo * 4 + r) * 32 + lr + 16 * kt];

  // scores (wave = head w)
  f32x4 sc[2] = {};
#pragma unroll
  for (int ks = 0; ks < 2; ++ks) {
    short8v aq = *(const short8v*)(qb + lr * 512 + nw + ks * 32 + lo * 8);
#pragma unroll
    for (int kt = 0; kt < 2; ++kt) {
      short8v b = *(const short8v*)(kb + (lr + 16 * kt) * 512 + nw + ks * 32 + lo * 8);
      sc[kt] = __builtin_amdgcn_mfma_f32_16x16x32_bf16(aq, b, sc[kt], 0, 0, 0);
    }
  }
  // softmax + p LDS + top
  float attn8[8];
  {
    float s8[8];
#pragma unroll
    for (int kt = 0; kt < 2; ++kt)
#pragma unroll
      for (int r = 0; r < 4; ++r) s8[kt * 4 + r] = sc[kt][r] + bias8[kt * 4 + r];
#pragma unroll
    for (int r = 0; r < 4; ++r) {
      float mx = fmaxf(s8[r], s8[4 + r]);
#pragma unroll
      for (int off = 1; off < 16; off <<= 1) mx = fmaxf(mx, __shfl_xor(mx, off, 16));
      float p0 = expf(s8[r] - mx), p1 = expf(s8[4 + r] - mx);
      float sm = p0 + p1;
#pragma unroll
      for (int off = 1; off < 16; off <<= 1) sm += __shfl_xor(sm, off, 16);
      float inv = 1.f / sm;
      attn8[r] = p0 * inv;
      attn8[4 + r] = p1 * inv;
    }
#pragma unroll
    for (int kt = 0; kt < 2; ++kt)
#pragma unroll
      for (int r = 0; r < 4; ++r) {
        int q = lo * 4 + r, key = lr + 16 * kt;
        *(short*)(smem + w * 1280 + q * 80 + key * 2) = bf16b(attn8[kt * 4 + r]);
        if (((w & 3) == 0) && lo < 2)
          top[(((size_t)bl * 16 + 2 * e + (w >> 2)) * 32 + 4 * q + (key >> 3)) * 8 + (key & 7)] =
              attn8[kt * 4 + r];
      }
  }

  // PV (wave-local p; in-order LDS per wave)
  {
    f32x4 xacc[4] = {};
    short8v ap = *(const short8v*)(smem + w * 1280 + lr * 80 + lo * 16);
#pragma unroll
    for (int nt = 0; nt < 4; ++nt) {
      short8v b = *(const short8v*)(vb + (nw + nt * 16 + lr) * 32 + lo * 8);
      xacc[nt] = __builtin_amdgcn_mfma_f32_16x16x32_bf16(ap, b, xacc[nt], 0, 0, 0);
    }
#pragma unroll
    for (int nt = 0; nt < 4; ++nt)
#pragma unroll
      for (int r = 0; r < 4; ++r)
        *(short*)(smem + 10240 + (lo * 4 + r) * 1040 + (nw + nt * 16 + lr) * 2) =
            bf16b(xacc[nt][r]);
  }
  __syncthreads();

  // coalesced x copy-out (overwrites this ble's consumed qp region)
  {
    short* xg = xbuf + (size_t)ble * 8192;
    const int row = t >> 5, c0 = (t & 31) * 16;
    *(short8v*)(xg + row * 512 + c0) = *(const short8v*)(smem + 10240 + row * 1040 + c0 * 2);
    *(short8v*)(xg + row * 512 + c0 + 8) =
        *(const short8v*)(smem + 10240 + row * 1040 + (c0 + 8) * 2);
  }
}

// ---- out GEMM v2: 16 rows x 512 cols, NO LDS, NO barriers; x bf16 in ws ----
__global__ __launch_bounds__(THREADS, 8) void out_v2(const short* __restrict__ x,
                                                     const float* __restrict__ bo,
                                                     const short* __restrict__ wt,
                                                     float* __restrict__ out) {
  const int t = threadIdx.x, lane = t & 63, w = t >> 6;
  const int lr = lane & 15, lo = lane >> 4;
  const int nw = w * 64;
  const int R0 = blockIdx.x * 16;

  const short* xr = x + (size_t)(R0 + lr) * 512;
  f32x4 acc[4] = {};
#pragma unroll
  for (int ks = 0; ks < 16; ++ks) {
    short8v a = *(const short8v*)(xr + ks * 32 + lo * 8);
#pragma unroll
    for (int nt = 0; nt < 4; ++nt) {
      short8v b = *(const short8v*)(wt + (((size_t)(1536 + nw + nt * 16 + lr)) << 9) +
                                    ks * 32 + lo * 8);
      acc[nt] = __builtin_amdgcn_mfma_f32_16x16x32_bf16(a, b, acc[nt], 0, 0, 0);
    }
  }
#pragma unroll
  for (int nt = 0; nt < 4; ++nt) {
    int n = nw + nt * 16 + lr;
    float bb = bo[n];
#pragma unroll
    for (int r = 0; r < 4; ++r)
      out[(size_t)(R0 + lo * 4 + r) * 512 + n] = acc[nt][r] + bb;
  }
}

extern "C" void kernel_launch(void* const* d_in, const int* in_sizes, int n_in,
                              void* d_out, int out_size, void* d_ws, size_t ws_size,
                              hipStream_t stream) {
  const float* query = (const float*)d_in[0];
  const float* key_a = (const float*)d_in[1];
  const float* val_a = (const float*)d_in[2];
  const float* bias = (const float*)d_in[3];
  const float* Wq = (const float*)d_in[4];
  const float* bq = (const float*)d_in[5];
  const float* Wk = (const float*)d_in[6];
  const float* bk = (const float*)d_in[7];
  const float* Wv = (const float*)d_in[8];
  const float* bv = (const float*)d_in[9];
  const float* Wo = (const float*)d_in[10];
  const float* bo = (const float*)d_in[11];
  float* out = (float*)d_out;
  float* top = out + 16777216;

  short* wt = (short*)d_ws;
  short* qpw = (short*)((char*)d_ws + 2097152);   // x aliases this after attn_mid
  short* kpw = (short*)((char*)d_ws + 35651584);
  short* vpw = (short*)((char*)d_ws + 102760448);

  prep_w<<<1024, 256, 0, stream>>>(Wq, Wk, Wv, Wo, wt);
  proj_v3<0><<<2048, THREADS, 0, stream>>>(query, bq, wt, qpw);
  proj_v3<1><<<4096, THREADS, 0, stream>>>(key_a, bk, wt, kpw);
  proj_v3<2><<<4096, THREADS, 0, stream>>>(val_a, bv, wt, vpw);
  attn_mid<<<2048, THREADS, 26880, stream>>>(qpw, kpw, vpw, bias, qpw, top);
  out_v2<<<2048, THREADS, 0, stream>>>(qpw, bo, wt, out);
}

// Round 18
// 308.113 us; speedup vs baseline: 3.5725x; 3.5725x over previous
//
#include <hip/hip_runtime.h>
#include <hip/hip_bf16.h>

// Shapes (fixed): B=4, L=64, E=8, Q=16, K=32, H=512, NH=8, HD=64
// R18: m97-style GEMM pipeline (global_load_lds + dbuf LDS + ds_read frags).
// R13-R17 lesson: hipcc never pipelines global->MFMA register chains (VGPR pinned
// 32-84, MfmaUtil 3-12%). The guide's proven fix is the m97 structure (874 TF).
//  - proj_p<MAT>: 128x128 tile, BK=32, A f32 staged via global_load_lds (cvt after
//    ds_read), B = wt bf16. XOR swizzle A slot^=(row&7), B slot^=((n>>1)&3);
//    linear LDS dest + pre-swizzled global src + swizzled read (rule #21).
//    48KB LDS -> 3 blocks/CU. K/Q epilogue bounces C via LDS (coalesced 16B).
//  - out_p: same, A bf16 (no cvt), 32KB LDS.
//  - attn_mid, prep_w verbatim (passed R16/R17).
// ws (proven >= 169,869,312): wt@0 2MB | qp@2M (x aliases) | kp@35.65M | vpT@102.76M.

#define THREADS 512

typedef __attribute__((ext_vector_type(8))) short short8v;
typedef __attribute__((ext_vector_type(4))) short short4v;
typedef __attribute__((ext_vector_type(4))) float f32x4;

__device__ __forceinline__ short bf16b(float f) {
  __hip_bfloat16 h = __float2bfloat16(f);
  return *reinterpret_cast<short*>(&h);
}

__device__ __forceinline__ void gl16(const void* g, void* l) {
  __builtin_amdgcn_global_load_lds(
      (const __attribute__((address_space(1))) unsigned int*)g,
      (__attribute__((address_space(3))) unsigned int*)l, 16, 0, 0);
}

// ---- W prep: wt[mat][n][k] = bf16(W[k][n]) ----
__global__ __launch_bounds__(256) void prep_w(const float* __restrict__ Wq,
                                              const float* __restrict__ Wk,
                                              const float* __restrict__ Wv,
                                              const float* __restrict__ Wo,
                                              short* __restrict__ wt) {
  __shared__ float tile[32][33];
  const int mat = blockIdx.x >> 8;
  const int tix = blockIdx.x & 255;
  const int n0 = (tix & 15) * 32, k0 = (tix >> 4) * 32;
  const float* W = (mat == 0) ? Wq : (mat == 1) ? Wk : (mat == 2) ? Wv : Wo;
  const int tx = threadIdx.x & 31, ty = threadIdx.x >> 5;
#pragma unroll
  for (int i = 0; i < 4; ++i)
    tile[ty + 8 * i][tx] = W[(size_t)(k0 + ty + 8 * i) * 512 + n0 + tx];
  __syncthreads();
#pragma unroll
  for (int i = 0; i < 4; ++i) {
    int n = ty + 8 * i, k = tx;
    wt[((size_t)(mat * 512 + n0 + n) << 9) + k0 + k] = bf16b(tile[k][n]);
  }
}

// ---- m97-style projection GEMM: 128x128 tile, BK=32, dbuf LDS ----
// MAT 0=Q(x0.125), 1=K, 2=V(transposed vpT). LDS: A f32 [2][128][32] @0 (16KB ea),
// B bf16 [2][128][32] @32768 (8KB ea). C-bounce tile aliases A region.
template <int MAT>
__global__ __launch_bounds__(256, 3) void proj_p(const float* __restrict__ A,
                                                 const float* __restrict__ bvec,
                                                 const short* __restrict__ wt,
                                                 short* __restrict__ C) {
  extern __shared__ char lds[];
  const int t = threadIdx.x, lane = t & 63, w = t >> 6;
  const int lr = lane & 15, lo = lane >> 4;
  const int wr = w >> 1, wc = w & 1;
  const int N0 = blockIdx.x * 128, R0 = blockIdx.y * 128;

  auto stage = [&](int buf, int k0) {
#pragma unroll
    for (int j = 0; j < 4; ++j) {  // A: 1024 chunks of 16B
      int c = j * 256 + t;
      int row = c >> 3, p = c & 7;
      int sl = p ^ (row & 7);
      gl16(&A[(size_t)(R0 + row) * 512 + k0 + sl * 4],
           lds + buf * 16384 + (j * 256 + w * 64) * 16);
    }
#pragma unroll
    for (int j = 0; j < 2; ++j) {  // B: 512 chunks of 16B
      int c = j * 256 + t;
      int n = c >> 2, p = c & 3;
      int sl = p ^ ((n >> 1) & 3);
      gl16(wt + (((size_t)(MAT * 512 + N0 + n)) << 9) + k0 + sl * 8,
           lds + 32768 + buf * 8192 + (j * 256 + w * 64) * 16);
    }
  };

  f32x4 acc[4][4] = {};
  int buf = 0;
  stage(0, 0);
  __syncthreads();
#pragma unroll
  for (int step = 0; step < 16; ++step) {
    if (step < 15) stage(buf ^ 1, (step + 1) * 32);
    short8v amt[4];
#pragma unroll
    for (int mt = 0; mt < 4; ++mt) {
      int row = wr * 64 + mt * 16 + lr;
      const char* ab = lds + buf * 16384 + row * 128;
      f32x4 a0 = *(const f32x4*)(ab + ((lo * 2) ^ (row & 7)) * 16);
      f32x4 a1 = *(const f32x4*)(ab + ((lo * 2 + 1) ^ (row & 7)) * 16);
      short8v a = {bf16b(a0.x), bf16b(a0.y), bf16b(a0.z), bf16b(a0.w),
                   bf16b(a1.x), bf16b(a1.y), bf16b(a1.z), bf16b(a1.w)};
      amt[mt] = a;
    }
#pragma unroll
    for (int nt = 0; nt < 4; ++nt) {
      int n = wc * 64 + nt * 16 + lr;
      short8v b = *(const short8v*)(lds + 32768 + buf * 8192 + n * 64 +
                                    (lo ^ ((n >> 1) & 3)) * 16);
#pragma unroll
      for (int mt = 0; mt < 4; ++mt)
        acc[mt][nt] = __builtin_amdgcn_mfma_f32_16x16x32_bf16(amt[mt], b, acc[mt][nt], 0, 0, 0);
    }
    __syncthreads();
    buf ^= 1;
  }

  if (MAT == 2) {
    // direct transposed store: vpT[ble][n][key], 4 consecutive keys per lane
#pragma unroll
    for (int nt = 0; nt < 4; ++nt) {
      int n = N0 + wc * 64 + nt * 16 + lr;
      float bb = bvec[n];
#pragma unroll
      for (int mt = 0; mt < 4; ++mt) {
        int grow = R0 + wr * 64 + mt * 16 + lo * 4;
        int ble2 = grow >> 5, key0 = grow & 31;
        short4v s4 = {bf16b(acc[mt][nt][0] + bb), bf16b(acc[mt][nt][1] + bb),
                      bf16b(acc[mt][nt][2] + bb), bf16b(acc[mt][nt][3] + bb)};
        *(short4v*)(C + (size_t)ble2 * 16384 + n * 32 + key0) = s4;
      }
    }
  } else {
    // LDS-bounce epilogue for coalesced 16B stores. Ct[128][136] shorts @0.
    short* Ct = (short*)lds;
#pragma unroll
    for (int nt = 0; nt < 4; ++nt) {
      int nl = wc * 64 + nt * 16 + lr;
      float bb = bvec[N0 + nl];
#pragma unroll
      for (int mt = 0; mt < 4; ++mt)
#pragma unroll
        for (int r = 0; r < 4; ++r) {
          int rowl = wr * 64 + mt * 16 + lo * 4 + r;
          float v = acc[mt][nt][r] + bb;
          Ct[rowl * 136 + nl] = bf16b(MAT == 0 ? v * 0.125f : v);
        }
    }
    __syncthreads();
#pragma unroll
    for (int j = 0; j < 8; ++j) {
      int idx = j * 256 + t;
      int row = idx >> 4, cc = idx & 15;
      short8v v = *(const short8v*)(Ct + row * 136 + cc * 8);
      int grow = R0 + row;
      if (MAT == 0)
        *(short8v*)(C + (size_t)(grow >> 4) * 8192 + (grow & 15) * 512 + N0 + cc * 8) = v;
      else
        *(short8v*)(C + (size_t)(grow >> 5) * 16384 + (grow & 31) * 512 + N0 + cc * 8) = v;
    }
  }
}

// ---- attention mid: scores + softmax + top + PV -> x (bf16, aliases qp) ----
__global__ __launch_bounds__(THREADS, 4) void attn_mid(
    const short* __restrict__ qp, const short* __restrict__ kp, const short* __restrict__ vpT,
    const float* __restrict__ bias, short* __restrict__ xbuf, float* __restrict__ top) {
  extern __shared__ char smem[];  // p[8][16][40]s @0 (10240B) ; x[16][520]s @10240
  const int t = threadIdx.x, lane = t & 63, w = t >> 6;
  const int ble = blockIdx.x, e = ble & 7, bl = ble >> 3;
  const int lr = lane & 15, lo = lane >> 4;
  const int nw = w * 64;

  const short* qb = qp + (size_t)ble * 8192;
  const short* kb = kp + (size_t)ble * 16384;
  const short* vb = vpT + (size_t)ble * 16384;

  const float* brow = bias + (size_t)ble * 512;
  float bias8[8];
#pragma unroll
  for (int kt = 0; kt < 2; ++kt)
#pragma unroll
    for (int r = 0; r < 4; ++r)
      bias8[kt * 4 + r] = brow[(lo * 4 + r) * 32 + lr + 16 * kt];

  f32x4 sc[2] = {};
#pragma unroll
  for (int ks = 0; ks < 2; ++ks) {
    short8v aq = *(const short8v*)(qb + lr * 512 + nw + ks * 32 + lo * 8);
#pragma unroll
    for (int kt = 0; kt < 2; ++kt) {
      short8v b = *(const short8v*)(kb + (lr + 16 * kt) * 512 + nw + ks * 32 + lo * 8);
      sc[kt] = __builtin_amdgcn_mfma_f32_16x16x32_bf16(aq, b, sc[kt], 0, 0, 0);
    }
  }
  float attn8[8];
  {
    float s8[8];
#pragma unroll
    for (int kt = 0; kt < 2; ++kt)
#pragma unroll
      for (int r = 0; r < 4; ++r) s8[kt * 4 + r] = sc[kt][r] + bias8[kt * 4 + r];
#pragma unroll
    for (int r = 0; r < 4; ++r) {
      float mx = fmaxf(s8[r], s8[4 + r]);
#pragma unroll
      for (int off = 1; off < 16; off <<= 1) mx = fmaxf(mx, __shfl_xor(mx, off, 16));
      float p0 = expf(s8[r] - mx), p1 = expf(s8[4 + r] - mx);
      float sm = p0 + p1;
#pragma unroll
      for (int off = 1; off < 16; off <<= 1) sm += __shfl_xor(sm, off, 16);
      float inv = 1.f / sm;
      attn8[r] = p0 * inv;
      attn8[4 + r] = p1 * inv;
    }
#pragma unroll
    for (int kt = 0; kt < 2; ++kt)
#pragma unroll
      for (int r = 0; r < 4; ++r) {
        int q = lo * 4 + r, key = lr + 16 * kt;
        *(short*)(smem + w * 1280 + q * 80 + key * 2) = bf16b(attn8[kt * 4 + r]);
        if (((w & 3) == 0) && lo < 2)
          top[(((size_t)bl * 16 + 2 * e + (w >> 2)) * 32 + 4 * q + (key >> 3)) * 8 + (key & 7)] =
              attn8[kt * 4 + r];
      }
  }
  {
    f32x4 xacc[4] = {};
    short8v ap = *(const short8v*)(smem + w * 1280 + lr * 80 + lo * 16);
#pragma unroll
    for (int nt = 0; nt < 4; ++nt) {
      short8v b = *(const short8v*)(vb + (nw + nt * 16 + lr) * 32 + lo * 8);
      xacc[nt] = __builtin_amdgcn_mfma_f32_16x16x32_bf16(ap, b, xacc[nt], 0, 0, 0);
    }
#pragma unroll
    for (int nt = 0; nt < 4; ++nt)
#pragma unroll
      for (int r = 0; r < 4; ++r)
        *(short*)(smem + 10240 + (lo * 4 + r) * 1040 + (nw + nt * 16 + lr) * 2) =
            bf16b(xacc[nt][r]);
  }
  __syncthreads();
  {
    short* xg = xbuf + (size_t)ble * 8192;
    const int row = t >> 5, c0 = (t & 31) * 16;
    *(short8v*)(xg + row * 512 + c0) = *(const short8v*)(smem + 10240 + row * 1040 + c0 * 2);
    *(short8v*)(xg + row * 512 + c0 + 8) =
        *(const short8v*)(smem + 10240 + row * 1040 + (c0 + 8) * 2);
  }
}

// ---- m97-style out GEMM: out[32768][512] f32 = x(bf16) @ Wo + bo ----
// LDS: A bf16 [2][128][32] @0 (8KB ea), B bf16 [2][128][32] @16384 (8KB ea) = 32KB.
__global__ __launch_bounds__(256, 4) void out_p(const short* __restrict__ x,
                                                const float* __restrict__ bo,
                                                const short* __restrict__ wt,
                                                float* __restrict__ out) {
  extern __shared__ char lds[];
  const int t = threadIdx.x, lane = t & 63, w = t >> 6;
  const int lr = lane & 15, lo = lane >> 4;
  const int wr = w >> 1, wc = w & 1;
  const int N0 = blockIdx.x * 128, R0 = blockIdx.y * 128;

  auto stage = [&](int buf, int k0) {
#pragma unroll
    for (int j = 0; j < 2; ++j) {  // A: 512 chunks
      int c = j * 256 + t;
      int row = c >> 2, p = c & 3;
      int sl = p ^ ((row >> 1) & 3);
      gl16(x + (size_t)(R0 + row) * 512 + k0 + sl * 8,
           lds + buf * 8192 + (j * 256 + w * 64) * 16);
    }
#pragma unroll
    for (int j = 0; j < 2; ++j) {  // B: 512 chunks
      int c = j * 256 + t;
      int n = c >> 2, p = c & 3;
      int sl = p ^ ((n >> 1) & 3);
      gl16(wt + (((size_t)(1536 + N0 + n)) << 9) + k0 + sl * 8,
           lds + 16384 + buf * 8192 + (j * 256 + w * 64) * 16);
    }
  };

  f32x4 acc[4][4] = {};
  int buf = 0;
  stage(0, 0);
  __syncthreads();
#pragma unroll
  for (int step = 0; step < 16; ++step) {
    if (step < 15) stage(buf ^ 1, (step + 1) * 32);
    short8v amt[4];
#pragma unroll
    for (int mt = 0; mt < 4; ++mt) {
      int row = wr * 64 + mt * 16 + lr;
      amt[mt] = *(const short8v*)(lds + buf * 8192 + row * 64 + (lo ^ ((row >> 1) & 3)) * 16);
    }
#pragma unroll
    for (int nt = 0; nt < 4; ++nt) {
      int n = wc * 64 + nt * 16 + lr;
      short8v b = *(const short8v*)(lds + 16384 + buf * 8192 + n * 64 +
                                    (lo ^ ((n >> 1) & 3)) * 16);
#pragma unroll
      for (int mt = 0; mt < 4; ++mt)
        acc[mt][nt] = __builtin_amdgcn_mfma_f32_16x16x32_bf16(amt[mt], b, acc[mt][nt], 0, 0, 0);
    }
    __syncthreads();
    buf ^= 1;
  }

#pragma unroll
  for (int nt = 0; nt < 4; ++nt) {
    int n = N0 + wc * 64 + nt * 16 + lr;
    float bb = bo[n];
#pragma unroll
    for (int mt = 0; mt < 4; ++mt)
#pragma unroll
      for (int r = 0; r < 4; ++r)
        out[(size_t)(R0 + wr * 64 + mt * 16 + lo * 4 + r) * 512 + n] = acc[mt][nt][r] + bb;
  }
}

extern "C" void kernel_launch(void* const* d_in, const int* in_sizes, int n_in,
                              void* d_out, int out_size, void* d_ws, size_t ws_size,
                              hipStream_t stream) {
  const float* query = (const float*)d_in[0];
  const float* key_a = (const float*)d_in[1];
  const float* val_a = (const float*)d_in[2];
  const float* bias = (const float*)d_in[3];
  const float* Wq = (const float*)d_in[4];
  const float* bq = (const float*)d_in[5];
  const float* Wk = (const float*)d_in[6];
  const float* bk = (const float*)d_in[7];
  const float* Wv = (const float*)d_in[8];
  const float* bv = (const float*)d_in[9];
  const float* Wo = (const float*)d_in[10];
  const float* bo = (const float*)d_in[11];
  float* out = (float*)d_out;
  float* top = out + 16777216;

  short* wt = (short*)d_ws;
  short* qpw = (short*)((char*)d_ws + 2097152);  // x aliases this after attn_mid
  short* kpw = (short*)((char*)d_ws + 35651584);
  short* vpw = (short*)((char*)d_ws + 102760448);

  prep_w<<<1024, 256, 0, stream>>>(Wq, Wk, Wv, Wo, wt);
  proj_p<0><<<dim3(4, 256), 256, 49152, stream>>>(query, bq, wt, qpw);
  proj_p<1><<<dim3(4, 512), 256, 49152, stream>>>(key_a, bk, wt, kpw);
  proj_p<2><<<dim3(4, 512), 256, 49152, stream>>>(val_a, bv, wt, vpw);
  attn_mid<<<2048, THREADS, 26880, stream>>>(qpw, kpw, vpw, bias, qpw, top);
  out_p<<<dim3(4, 256), 256, 32768, stream>>>(qpw, bo, wt, out);
}

// Round 19
// 268.791 us; speedup vs baseline: 4.0951x; 1.1463x over previous
//
#include <hip/hip_runtime.h>
#include <hip/hip_bf16.h>

// Shapes (fixed): B=4, L=64, E=8, Q=16, K=32, H=512, NH=8, HD=64
// R19: R18 (m97-style pipeline, 308us) + XCD-locality grid swizzle on proj_p/out_p.
// R18 diagnosis: K/V proj FETCH=263MB vs 134MB input (4 N-blocks re-read the same
// A stripe from 4 different XCD L2s). Fix: bid=((rg*4+nn)<<3)|xcd so the 4 sharers
// are consecutive on ONE XCD (block->XCD = bid%8): A stripe stays in that L2.
// Everything else verbatim from R18 (passed, absmax 9.77e-4).
// ws (proven >= 169,869,312): wt@0 2MB | qp@2M (x aliases) | kp@35.65M | vpT@102.76M.

#define THREADS 512

typedef __attribute__((ext_vector_type(8))) short short8v;
typedef __attribute__((ext_vector_type(4))) short short4v;
typedef __attribute__((ext_vector_type(4))) float f32x4;

__device__ __forceinline__ short bf16b(float f) {
  __hip_bfloat16 h = __float2bfloat16(f);
  return *reinterpret_cast<short*>(&h);
}

__device__ __forceinline__ void gl16(const void* g, void* l) {
  __builtin_amdgcn_global_load_lds(
      (const __attribute__((address_space(1))) unsigned int*)g,
      (__attribute__((address_space(3))) unsigned int*)l, 16, 0, 0);
}

// ---- W prep: wt[mat][n][k] = bf16(W[k][n]) ----
__global__ __launch_bounds__(256) void prep_w(const float* __restrict__ Wq,
                                              const float* __restrict__ Wk,
                                              const float* __restrict__ Wv,
                                              const float* __restrict__ Wo,
                                              short* __restrict__ wt) {
  __shared__ float tile[32][33];
  const int mat = blockIdx.x >> 8;
  const int tix = blockIdx.x & 255;
  const int n0 = (tix & 15) * 32, k0 = (tix >> 4) * 32;
  const float* W = (mat == 0) ? Wq : (mat == 1) ? Wk : (mat == 2) ? Wv : Wo;
  const int tx = threadIdx.x & 31, ty = threadIdx.x >> 5;
#pragma unroll
  for (int i = 0; i < 4; ++i)
    tile[ty + 8 * i][tx] = W[(size_t)(k0 + ty + 8 * i) * 512 + n0 + tx];
  __syncthreads();
#pragma unroll
  for (int i = 0; i < 4; ++i) {
    int n = ty + 8 * i, k = tx;
    wt[((size_t)(mat * 512 + n0 + n) << 9) + k0 + k] = bf16b(tile[k][n]);
  }
}

// ---- m97-style projection GEMM: 128x128 tile, BK=32, dbuf LDS, XCD-swizzled grid ----
// MAT 0=Q(x0.125), 1=K, 2=V(transposed vpT). 1D grid = nRB*4 blocks (nRB multiple of 8).
template <int MAT>
__global__ __launch_bounds__(256, 3) void proj_p(const float* __restrict__ A,
                                                 const float* __restrict__ bvec,
                                                 const short* __restrict__ wt,
                                                 short* __restrict__ C) {
  extern __shared__ char lds[];
  const int t = threadIdx.x, lane = t & 63, w = t >> 6;
  const int lr = lane & 15, lo = lane >> 4;
  const int wr = w >> 1, wc = w & 1;
  // XCD-locality decode: 4 N-blocks of one R-stripe are consecutive on one XCD
  const int bid = blockIdx.x;
  const int xcd = bid & 7, tt = bid >> 3;
  const int nn = tt & 3, rg = tt >> 2;
  const int R0 = (rg * 8 + xcd) * 128, N0 = nn * 128;

  auto stage = [&](int buf, int k0) {
#pragma unroll
    for (int j = 0; j < 4; ++j) {  // A: 1024 chunks of 16B
      int c = j * 256 + t;
      int row = c >> 3, p = c & 7;
      int sl = p ^ (row & 7);
      gl16(&A[(size_t)(R0 + row) * 512 + k0 + sl * 4],
           lds + buf * 16384 + (j * 256 + w * 64) * 16);
    }
#pragma unroll
    for (int j = 0; j < 2; ++j) {  // B: 512 chunks of 16B
      int c = j * 256 + t;
      int n = c >> 2, p = c & 3;
      int sl = p ^ ((n >> 1) & 3);
      gl16(wt + (((size_t)(MAT * 512 + N0 + n)) << 9) + k0 + sl * 8,
           lds + 32768 + buf * 8192 + (j * 256 + w * 64) * 16);
    }
  };

  f32x4 acc[4][4] = {};
  int buf = 0;
  stage(0, 0);
  __syncthreads();
#pragma unroll
  for (int step = 0; step < 16; ++step) {
    if (step < 15) stage(buf ^ 1, (step + 1) * 32);
    short8v amt[4];
#pragma unroll
    for (int mt = 0; mt < 4; ++mt) {
      int row = wr * 64 + mt * 16 + lr;
      const char* ab = lds + buf * 16384 + row * 128;
      f32x4 a0 = *(const f32x4*)(ab + ((lo * 2) ^ (row & 7)) * 16);
      f32x4 a1 = *(const f32x4*)(ab + ((lo * 2 + 1) ^ (row & 7)) * 16);
      short8v a = {bf16b(a0.x), bf16b(a0.y), bf16b(a0.z), bf16b(a0.w),
                   bf16b(a1.x), bf16b(a1.y), bf16b(a1.z), bf16b(a1.w)};
      amt[mt] = a;
    }
#pragma unroll
    for (int nt = 0; nt < 4; ++nt) {
      int n = wc * 64 + nt * 16 + lr;
      short8v b = *(const short8v*)(lds + 32768 + buf * 8192 + n * 64 +
                                    (lo ^ ((n >> 1) & 3)) * 16);
#pragma unroll
      for (int mt = 0; mt < 4; ++mt)
        acc[mt][nt] = __builtin_amdgcn_mfma_f32_16x16x32_bf16(amt[mt], b, acc[mt][nt], 0, 0, 0);
    }
    __syncthreads();
    buf ^= 1;
  }

  if (MAT == 2) {
#pragma unroll
    for (int nt = 0; nt < 4; ++nt) {
      int n = N0 + wc * 64 + nt * 16 + lr;
      float bb = bvec[n];
#pragma unroll
      for (int mt = 0; mt < 4; ++mt) {
        int grow = R0 + wr * 64 + mt * 16 + lo * 4;
        int ble2 = grow >> 5, key0 = grow & 31;
        short4v s4 = {bf16b(acc[mt][nt][0] + bb), bf16b(acc[mt][nt][1] + bb),
                      bf16b(acc[mt][nt][2] + bb), bf16b(acc[mt][nt][3] + bb)};
        *(short4v*)(C + (size_t)ble2 * 16384 + n * 32 + key0) = s4;
      }
    }
  } else {
    short* Ct = (short*)lds;
#pragma unroll
    for (int nt = 0; nt < 4; ++nt) {
      int nl = wc * 64 + nt * 16 + lr;
      float bb = bvec[N0 + nl];
#pragma unroll
      for (int mt = 0; mt < 4; ++mt)
#pragma unroll
        for (int r = 0; r < 4; ++r) {
          int rowl = wr * 64 + mt * 16 + lo * 4 + r;
          float v = acc[mt][nt][r] + bb;
          Ct[rowl * 136 + nl] = bf16b(MAT == 0 ? v * 0.125f : v);
        }
    }
    __syncthreads();
#pragma unroll
    for (int j = 0; j < 8; ++j) {
      int idx = j * 256 + t;
      int row = idx >> 4, cc = idx & 15;
      short8v v = *(const short8v*)(Ct + row * 136 + cc * 8);
      int grow = R0 + row;
      if (MAT == 0)
        *(short8v*)(C + (size_t)(grow >> 4) * 8192 + (grow & 15) * 512 + N0 + cc * 8) = v;
      else
        *(short8v*)(C + (size_t)(grow >> 5) * 16384 + (grow & 31) * 512 + N0 + cc * 8) = v;
    }
  }
}

// ---- attention mid: scores + softmax + top + PV -> x (bf16, aliases qp) ----
__global__ __launch_bounds__(THREADS, 4) void attn_mid(
    const short* __restrict__ qp, const short* __restrict__ kp, const short* __restrict__ vpT,
    const float* __restrict__ bias, short* __restrict__ xbuf, float* __restrict__ top) {
  extern __shared__ char smem[];  // p[8][16][40]s @0 (10240B) ; x[16][520]s @10240
  const int t = threadIdx.x, lane = t & 63, w = t >> 6;
  const int ble = blockIdx.x, e = ble & 7, bl = ble >> 3;
  const int lr = lane & 15, lo = lane >> 4;
  const int nw = w * 64;

  const short* qb = qp + (size_t)ble * 8192;
  const short* kb = kp + (size_t)ble * 16384;
  const short* vb = vpT + (size_t)ble * 16384;

  const float* brow = bias + (size_t)ble * 512;
  float bias8[8];
#pragma unroll
  for (int kt = 0; kt < 2; ++kt)
#pragma unroll
    for (int r = 0; r < 4; ++r)
      bias8[kt * 4 + r] = brow[(lo * 4 + r) * 32 + lr + 16 * kt];

  f32x4 sc[2] = {};
#pragma unroll
  for (int ks = 0; ks < 2; ++ks) {
    short8v aq = *(const short8v*)(qb + lr * 512 + nw + ks * 32 + lo * 8);
#pragma unroll
    for (int kt = 0; kt < 2; ++kt) {
      short8v b = *(const short8v*)(kb + (lr + 16 * kt) * 512 + nw + ks * 32 + lo * 8);
      sc[kt] = __builtin_amdgcn_mfma_f32_16x16x32_bf16(aq, b, sc[kt], 0, 0, 0);
    }
  }
  float attn8[8];
  {
    float s8[8];
#pragma unroll
    for (int kt = 0; kt < 2; ++kt)
#pragma unroll
      for (int r = 0; r < 4; ++r) s8[kt * 4 + r] = sc[kt][r] + bias8[kt * 4 + r];
#pragma unroll
    for (int r = 0; r < 4; ++r) {
      float mx = fmaxf(s8[r], s8[4 + r]);
#pragma unroll
      for (int off = 1; off < 16; off <<= 1) mx = fmaxf(mx, __shfl_xor(mx, off, 16));
      float p0 = expf(s8[r] - mx), p1 = expf(s8[4 + r] - mx);
      float sm = p0 + p1;
#pragma unroll
      for (int off = 1; off < 16; off <<= 1) sm += __shfl_xor(sm, off, 16);
      float inv = 1.f / sm;
      attn8[r] = p0 * inv;
      attn8[4 + r] = p1 * inv;
    }
#pragma unroll
    for (int kt = 0; kt < 2; ++kt)
#pragma unroll
      for (int r = 0; r < 4; ++r) {
        int q = lo * 4 + r, key = lr + 16 * kt;
        *(short*)(smem + w * 1280 + q * 80 + key * 2) = bf16b(attn8[kt * 4 + r]);
        if (((w & 3) == 0) && lo < 2)
          top[(((size_t)bl * 16 + 2 * e + (w >> 2)) * 32 + 4 * q + (key >> 3)) * 8 + (key & 7)] =
              attn8[kt * 4 + r];
      }
  }
  {
    f32x4 xacc[4] = {};
    short8v ap = *(const short8v*)(smem + w * 1280 + lr * 80 + lo * 16);
#pragma unroll
    for (int nt = 0; nt < 4; ++nt) {
      short8v b = *(const short8v*)(vb + (nw + nt * 16 + lr) * 32 + lo * 8);
      xacc[nt] = __builtin_amdgcn_mfma_f32_16x16x32_bf16(ap, b, xacc[nt], 0, 0, 0);
    }
#pragma unroll
    for (int nt = 0; nt < 4; ++nt)
#pragma unroll
      for (int r = 0; r < 4; ++r)
        *(short*)(smem + 10240 + (lo * 4 + r) * 1040 + (nw + nt * 16 + lr) * 2) =
            bf16b(xacc[nt][r]);
  }
  __syncthreads();
  {
    short* xg = xbuf + (size_t)ble * 8192;
    const int row = t >> 5, c0 = (t & 31) * 16;
    *(short8v*)(xg + row * 512 + c0) = *(const short8v*)(smem + 10240 + row * 1040 + c0 * 2);
    *(short8v*)(xg + row * 512 + c0 + 8) =
        *(const short8v*)(smem + 10240 + row * 1040 + (c0 + 8) * 2);
  }
}

// ---- m97-style out GEMM: out[32768][512] f32 = x(bf16) @ Wo + bo, XCD-swizzled ----
__global__ __launch_bounds__(256, 4) void out_p(const short* __restrict__ x,
                                                const float* __restrict__ bo,
                                                const short* __restrict__ wt,
                                                float* __restrict__ out) {
  extern __shared__ char lds[];
  const int t = threadIdx.x, lane = t & 63, w = t >> 6;
  const int lr = lane & 15, lo = lane >> 4;
  const int wr = w >> 1, wc = w & 1;
  const int bid = blockIdx.x;
  const int xcd = bid & 7, tt = bid >> 3;
  const int nn = tt & 3, rg = tt >> 2;
  const int R0 = (rg * 8 + xcd) * 128, N0 = nn * 128;

  auto stage = [&](int buf, int k0) {
#pragma unroll
    for (int j = 0; j < 2; ++j) {
      int c = j * 256 + t;
      int row = c >> 2, p = c & 3;
      int sl = p ^ ((row >> 1) & 3);
      gl16(x + (size_t)(R0 + row) * 512 + k0 + sl * 8,
           lds + buf * 8192 + (j * 256 + w * 64) * 16);
    }
#pragma unroll
    for (int j = 0; j < 2; ++j) {
      int c = j * 256 + t;
      int n = c >> 2, p = c & 3;
      int sl = p ^ ((n >> 1) & 3);
      gl16(wt + (((size_t)(1536 + N0 + n)) << 9) + k0 + sl * 8,
           lds + 16384 + buf * 8192 + (j * 256 + w * 64) * 16);
    }
  };

  f32x4 acc[4][4] = {};
  int buf = 0;
  stage(0, 0);
  __syncthreads();
#pragma unroll
  for (int step = 0; step < 16; ++step) {
    if (step < 15) stage(buf ^ 1, (step + 1) * 32);
    short8v amt[4];
#pragma unroll
    for (int mt = 0; mt < 4; ++mt) {
      int row = wr * 64 + mt * 16 + lr;
      amt[mt] = *(const short8v*)(lds + buf * 8192 + row * 64 + (lo ^ ((row >> 1) & 3)) * 16);
    }
#pragma unroll
    for (int nt = 0; nt < 4; ++nt) {
      int n = wc * 64 + nt * 16 + lr;
      short8v b = *(const short8v*)(lds + 16384 + buf * 8192 + n * 64 +
                                    (lo ^ ((n >> 1) & 3)) * 16);
#pragma unroll
      for (int mt = 0; mt < 4; ++mt)
        acc[mt][nt] = __builtin_amdgcn_mfma_f32_16x16x32_bf16(amt[mt], b, acc[mt][nt], 0, 0, 0);
    }
    __syncthreads();
    buf ^= 1;
  }

#pragma unroll
  for (int nt = 0; nt < 4; ++nt) {
    int n = N0 + wc * 64 + nt * 16 + lr;
    float bb = bo[n];
#pragma unroll
    for (int mt = 0; mt < 4; ++mt)
#pragma unroll
      for (int r = 0; r < 4; ++r)
        out[(size_t)(R0 + wr * 64 + mt * 16 + lo * 4 + r) * 512 + n] = acc[mt][nt][r] + bb;
  }
}

extern "C" void kernel_launch(void* const* d_in, const int* in_sizes, int n_in,
                              void* d_out, int out_size, void* d_ws, size_t ws_size,
                              hipStream_t stream) {
  const float* query = (const float*)d_in[0];
  const float* key_a = (const float*)d_in[1];
  const float* val_a = (const float*)d_in[2];
  const float* bias = (const float*)d_in[3];
  const float* Wq = (const float*)d_in[4];
  const float* bq = (const float*)d_in[5];
  const float* Wk = (const float*)d_in[6];
  const float* bk = (const float*)d_in[7];
  const float* Wv = (const float*)d_in[8];
  const float* bv = (const float*)d_in[9];
  const float* Wo = (const float*)d_in[10];
  const float* bo = (const float*)d_in[11];
  float* out = (float*)d_out;
  float* top = out + 16777216;

  short* wt = (short*)d_ws;
  short* qpw = (short*)((char*)d_ws + 2097152);  // x aliases this after attn_mid
  short* kpw = (short*)((char*)d_ws + 35651584);
  short* vpw = (short*)((char*)d_ws + 102760448);

  prep_w<<<1024, 256, 0, stream>>>(Wq, Wk, Wv, Wo, wt);
  proj_p<0><<<1024, 256, 49152, stream>>>(query, bq, wt, qpw);
  proj_p<1><<<2048, 256, 49152, stream>>>(key_a, bk, wt, kpw);
  proj_p<2><<<2048, 256, 49152, stream>>>(val_a, bv, wt, vpw);
  attn_mid<<<2048, THREADS, 26880, stream>>>(qpw, kpw, vpw, bias, qpw, top);
  out_p<<<1024, 256, 32768, stream>>>(qpw, bo, wt, out);
}

// Round 20
// 248.201 us; speedup vs baseline: 4.4348x; 1.0830x over previous
//
#include <hip/hip_runtime.h>
#include <hip/hip_bf16.h>

// Shapes (fixed): B=4, L=64, E=8, Q=16, K=32, H=512, NH=8, HD=64
// R20: fuse Q/K/V projections into ONE 5120-block launch (runtime MAT, block-range
// decode; branch-uniform). R19 evidence: each proj sits at the m97-structure plateau
// (~382 TF, MfmaUtil 15%, FETCH minimal after XCD swizzle) -> remaining waste is
// dispatch tails (~0.33 rounds x3) + inter-launch gaps. Fusion packs them.
// Math/mappings verbatim from R19 (passed, absmax 9.77e-4).
// ws (proven >= 169,869,312): wt@0 2MB | qp@2M (x aliases) | kp@35.65M | vpT@102.76M.

#define THREADS 512

typedef __attribute__((ext_vector_type(8))) short short8v;
typedef __attribute__((ext_vector_type(4))) short short4v;
typedef __attribute__((ext_vector_type(4))) float f32x4;

__device__ __forceinline__ short bf16b(float f) {
  __hip_bfloat16 h = __float2bfloat16(f);
  return *reinterpret_cast<short*>(&h);
}

__device__ __forceinline__ void gl16(const void* g, void* l) {
  __builtin_amdgcn_global_load_lds(
      (const __attribute__((address_space(1))) unsigned int*)g,
      (__attribute__((address_space(3))) unsigned int*)l, 16, 0, 0);
}

// ---- W prep: wt[mat][n][k] = bf16(W[k][n]) ----
__global__ __launch_bounds__(256) void prep_w(const float* __restrict__ Wq,
                                              const float* __restrict__ Wk,
                                              const float* __restrict__ Wv,
                                              const float* __restrict__ Wo,
                                              short* __restrict__ wt) {
  __shared__ float tile[32][33];
  const int mat = blockIdx.x >> 8;
  const int tix = blockIdx.x & 255;
  const int n0 = (tix & 15) * 32, k0 = (tix >> 4) * 32;
  const float* W = (mat == 0) ? Wq : (mat == 1) ? Wk : (mat == 2) ? Wv : Wo;
  const int tx = threadIdx.x & 31, ty = threadIdx.x >> 5;
#pragma unroll
  for (int i = 0; i < 4; ++i)
    tile[ty + 8 * i][tx] = W[(size_t)(k0 + ty + 8 * i) * 512 + n0 + tx];
  __syncthreads();
#pragma unroll
  for (int i = 0; i < 4; ++i) {
    int n = ty + 8 * i, k = tx;
    wt[((size_t)(mat * 512 + n0 + n) << 9) + k0 + k] = bf16b(tile[k][n]);
  }
}

// ---- fused Q/K/V projection: one launch, 5120 blocks ----
// Ranges: [0,2048)=K, [2048,4096)=V, [4096,5120)=Q. Per-range XCD-local decode
// (sub&7 = xcd; 4 N-blocks of an R-stripe consecutive on one XCD).
__global__ __launch_bounds__(256, 3) void proj_all(
    const float* __restrict__ Aq, const float* __restrict__ Ak, const float* __restrict__ Av,
    const float* __restrict__ bq, const float* __restrict__ bk, const float* __restrict__ bv,
    const short* __restrict__ wt, short* __restrict__ Cq, short* __restrict__ Ck,
    short* __restrict__ Cv) {
  extern __shared__ char lds[];
  const int t = threadIdx.x, lane = t & 63, w = t >> 6;
  const int lr = lane & 15, lo = lane >> 4;
  const int wr = w >> 1, wc = w & 1;

  int bid = blockIdx.x, MAT, sub;
  const float* A;
  const float* bvec;
  short* C;
  if (bid < 2048) {
    MAT = 1; sub = bid; A = Ak; bvec = bk; C = Ck;
  } else if (bid < 4096) {
    MAT = 2; sub = bid - 2048; A = Av; bvec = bv; C = Cv;
  } else {
    MAT = 0; sub = bid - 4096; A = Aq; bvec = bq; C = Cq;
  }
  const int xcd = sub & 7, tt = sub >> 3;
  const int nn = tt & 3, rg = tt >> 2;
  const int R0 = (rg * 8 + xcd) * 128, N0 = nn * 128;

  auto stage = [&](int buf, int k0) {
#pragma unroll
    for (int j = 0; j < 4; ++j) {  // A: 1024 chunks of 16B
      int c = j * 256 + t;
      int row = c >> 3, p = c & 7;
      int sl = p ^ (row & 7);
      gl16(&A[(size_t)(R0 + row) * 512 + k0 + sl * 4],
           lds + buf * 16384 + (j * 256 + w * 64) * 16);
    }
#pragma unroll
    for (int j = 0; j < 2; ++j) {  // B: 512 chunks of 16B
      int c = j * 256 + t;
      int n = c >> 2, p = c & 3;
      int sl = p ^ ((n >> 1) & 3);
      gl16(wt + (((size_t)(MAT * 512 + N0 + n)) << 9) + k0 + sl * 8,
           lds + 32768 + buf * 8192 + (j * 256 + w * 64) * 16);
    }
  };

  f32x4 acc[4][4] = {};
  int buf = 0;
  stage(0, 0);
  __syncthreads();
#pragma unroll
  for (int step = 0; step < 16; ++step) {
    if (step < 15) stage(buf ^ 1, (step + 1) * 32);
    short8v amt[4];
#pragma unroll
    for (int mt = 0; mt < 4; ++mt) {
      int row = wr * 64 + mt * 16 + lr;
      const char* ab = lds + buf * 16384 + row * 128;
      f32x4 a0 = *(const f32x4*)(ab + ((lo * 2) ^ (row & 7)) * 16);
      f32x4 a1 = *(const f32x4*)(ab + ((lo * 2 + 1) ^ (row & 7)) * 16);
      short8v a = {bf16b(a0.x), bf16b(a0.y), bf16b(a0.z), bf16b(a0.w),
                   bf16b(a1.x), bf16b(a1.y), bf16b(a1.z), bf16b(a1.w)};
      amt[mt] = a;
    }
#pragma unroll
    for (int nt = 0; nt < 4; ++nt) {
      int n = wc * 64 + nt * 16 + lr;
      short8v b = *(const short8v*)(lds + 32768 + buf * 8192 + n * 64 +
                                    (lo ^ ((n >> 1) & 3)) * 16);
#pragma unroll
      for (int mt = 0; mt < 4; ++mt)
        acc[mt][nt] = __builtin_amdgcn_mfma_f32_16x16x32_bf16(amt[mt], b, acc[mt][nt], 0, 0, 0);
    }
    __syncthreads();
    buf ^= 1;
  }

  if (MAT == 2) {
#pragma unroll
    for (int nt = 0; nt < 4; ++nt) {
      int n = N0 + wc * 64 + nt * 16 + lr;
      float bb = bvec[n];
#pragma unroll
      for (int mt = 0; mt < 4; ++mt) {
        int grow = R0 + wr * 64 + mt * 16 + lo * 4;
        int ble2 = grow >> 5, key0 = grow & 31;
        short4v s4 = {bf16b(acc[mt][nt][0] + bb), bf16b(acc[mt][nt][1] + bb),
                      bf16b(acc[mt][nt][2] + bb), bf16b(acc[mt][nt][3] + bb)};
        *(short4v*)(C + (size_t)ble2 * 16384 + n * 32 + key0) = s4;
      }
    }
  } else {
    short* Ct = (short*)lds;
    const float scale = (MAT == 0) ? 0.125f : 1.0f;
#pragma unroll
    for (int nt = 0; nt < 4; ++nt) {
      int nl = wc * 64 + nt * 16 + lr;
      float bb = bvec[N0 + nl];
#pragma unroll
      for (int mt = 0; mt < 4; ++mt)
#pragma unroll
        for (int r = 0; r < 4; ++r) {
          int rowl = wr * 64 + mt * 16 + lo * 4 + r;
          Ct[rowl * 136 + nl] = bf16b((acc[mt][nt][r] + bb) * scale);
        }
    }
    __syncthreads();
#pragma unroll
    for (int j = 0; j < 8; ++j) {
      int idx = j * 256 + t;
      int row = idx >> 4, cc = idx & 15;
      short8v v = *(const short8v*)(Ct + row * 136 + cc * 8);
      int grow = R0 + row;
      if (MAT == 0)
        *(short8v*)(C + (size_t)(grow >> 4) * 8192 + (grow & 15) * 512 + N0 + cc * 8) = v;
      else
        *(short8v*)(C + (size_t)(grow >> 5) * 16384 + (grow & 31) * 512 + N0 + cc * 8) = v;
    }
  }
}

// ---- attention mid: scores + softmax + top + PV -> x (bf16, aliases qp) ----
__global__ __launch_bounds__(THREADS, 4) void attn_mid(
    const short* __restrict__ qp, const short* __restrict__ kp, const short* __restrict__ vpT,
    const float* __restrict__ bias, short* __restrict__ xbuf, float* __restrict__ top) {
  extern __shared__ char smem[];  // p[8][16][40]s @0 (10240B) ; x[16][520]s @10240
  const int t = threadIdx.x, lane = t & 63, w = t >> 6;
  const int ble = blockIdx.x, e = ble & 7, bl = ble >> 3;
  const int lr = lane & 15, lo = lane >> 4;
  const int nw = w * 64;

  const short* qb = qp + (size_t)ble * 8192;
  const short* kb = kp + (size_t)ble * 16384;
  const short* vb = vpT + (size_t)ble * 16384;

  const float* brow = bias + (size_t)ble * 512;
  float bias8[8];
#pragma unroll
  for (int kt = 0; kt < 2; ++kt)
#pragma unroll
    for (int r = 0; r < 4; ++r)
      bias8[kt * 4 + r] = brow[(lo * 4 + r) * 32 + lr + 16 * kt];

  f32x4 sc[2] = {};
#pragma unroll
  for (int ks = 0; ks < 2; ++ks) {
    short8v aq = *(const short8v*)(qb + lr * 512 + nw + ks * 32 + lo * 8);
#pragma unroll
    for (int kt = 0; kt < 2; ++kt) {
      short8v b = *(const short8v*)(kb + (lr + 16 * kt) * 512 + nw + ks * 32 + lo * 8);
      sc[kt] = __builtin_amdgcn_mfma_f32_16x16x32_bf16(aq, b, sc[kt], 0, 0, 0);
    }
  }
  float attn8[8];
  {
    float s8[8];
#pragma unroll
    for (int kt = 0; kt < 2; ++kt)
#pragma unroll
      for (int r = 0; r < 4; ++r) s8[kt * 4 + r] = sc[kt][r] + bias8[kt * 4 + r];
#pragma unroll
    for (int r = 0; r < 4; ++r) {
      float mx = fmaxf(s8[r], s8[4 + r]);
#pragma unroll
      for (int off = 1; off < 16; off <<= 1) mx = fmaxf(mx, __shfl_xor(mx, off, 16));
      float p0 = expf(s8[r] - mx), p1 = expf(s8[4 + r] - mx);
      float sm = p0 + p1;
#pragma unroll
      for (int off = 1; off < 16; off <<= 1) sm += __shfl_xor(sm, off, 16);
      float inv = 1.f / sm;
      attn8[r] = p0 * inv;
      attn8[4 + r] = p1 * inv;
    }
#pragma unroll
    for (int kt = 0; kt < 2; ++kt)
#pragma unroll
      for (int r = 0; r < 4; ++r) {
        int q = lo * 4 + r, key = lr + 16 * kt;
        *(short*)(smem + w * 1280 + q * 80 + key * 2) = bf16b(attn8[kt * 4 + r]);
        if (((w & 3) == 0) && lo < 2)
          top[(((size_t)bl * 16 + 2 * e + (w >> 2)) * 32 + 4 * q + (key >> 3)) * 8 + (key & 7)] =
              attn8[kt * 4 + r];
      }
  }
  {
    f32x4 xacc[4] = {};
    short8v ap = *(const short8v*)(smem + w * 1280 + lr * 80 + lo * 16);
#pragma unroll
    for (int nt = 0; nt < 4; ++nt) {
      short8v b = *(const short8v*)(vb + (nw + nt * 16 + lr) * 32 + lo * 8);
      xacc[nt] = __builtin_amdgcn_mfma_f32_16x16x32_bf16(ap, b, xacc[nt], 0, 0, 0);
    }
#pragma unroll
    for (int nt = 0; nt < 4; ++nt)
#pragma unroll
      for (int r = 0; r < 4; ++r)
        *(short*)(smem + 10240 + (lo * 4 + r) * 1040 + (nw + nt * 16 + lr) * 2) =
            bf16b(xacc[nt][r]);
  }
  __syncthreads();
  {
    short* xg = xbuf + (size_t)ble * 8192;
    const int row = t >> 5, c0 = (t & 31) * 16;
    *(short8v*)(xg + row * 512 + c0) = *(const short8v*)(smem + 10240 + row * 1040 + c0 * 2);
    *(short8v*)(xg + row * 512 + c0 + 8) =
        *(const short8v*)(smem + 10240 + row * 1040 + (c0 + 8) * 2);
  }
}

// ---- m97-style out GEMM: out[32768][512] f32 = x(bf16) @ Wo + bo, XCD-swizzled ----
__global__ __launch_bounds__(256, 4) void out_p(const short* __restrict__ x,
                                                const float* __restrict__ bo,
                                                const short* __restrict__ wt,
                                                float* __restrict__ out) {
  extern __shared__ char lds[];
  const int t = threadIdx.x, lane = t & 63, w = t >> 6;
  const int lr = lane & 15, lo = lane >> 4;
  const int wr = w >> 1, wc = w & 1;
  const int bid = blockIdx.x;
  const int xcd = bid & 7, tt = bid >> 3;
  const int nn = tt & 3, rg = tt >> 2;
  const int R0 = (rg * 8 + xcd) * 128, N0 = nn * 128;

  auto stage = [&](int buf, int k0) {
#pragma unroll
    for (int j = 0; j < 2; ++j) {
      int c = j * 256 + t;
      int row = c >> 2, p = c & 3;
      int sl = p ^ ((row >> 1) & 3);
      gl16(x + (size_t)(R0 + row) * 512 + k0 + sl * 8,
           lds + buf * 8192 + (j * 256 + w * 64) * 16);
    }
#pragma unroll
    for (int j = 0; j < 2; ++j) {
      int c = j * 256 + t;
      int n = c >> 2, p = c & 3;
      int sl = p ^ ((n >> 1) & 3);
      gl16(wt + (((size_t)(1536 + N0 + n)) << 9) + k0 + sl * 8,
           lds + 16384 + buf * 8192 + (j * 256 + w * 64) * 16);
    }
  };

  f32x4 acc[4][4] = {};
  int buf = 0;
  stage(0, 0);
  __syncthreads();
#pragma unroll
  for (int step = 0; step < 16; ++step) {
    if (step < 15) stage(buf ^ 1, (step + 1) * 32);
    short8v amt[4];
#pragma unroll
    for (int mt = 0; mt < 4; ++mt) {
      int row = wr * 64 + mt * 16 + lr;
      amt[mt] = *(const short8v*)(lds + buf * 8192 + row * 64 + (lo ^ ((row >> 1) & 3)) * 16);
    }
#pragma unroll
    for (int nt = 0; nt < 4; ++nt) {
      int n = wc * 64 + nt * 16 + lr;
      short8v b = *(const short8v*)(lds + 16384 + buf * 8192 + n * 64 +
                                    (lo ^ ((n >> 1) & 3)) * 16);
#pragma unroll
      for (int mt = 0; mt < 4; ++mt)
        acc[mt][nt] = __builtin_amdgcn_mfma_f32_16x16x32_bf16(amt[mt], b, acc[mt][nt], 0, 0, 0);
    }
    __syncthreads();
    buf ^= 1;
  }

#pragma unroll
  for (int nt = 0; nt < 4; ++nt) {
    int n = N0 + wc * 64 + nt * 16 + lr;
    float bb = bo[n];
#pragma unroll
    for (int mt = 0; mt < 4; ++mt)
#pragma unroll
      for (int r = 0; r < 4; ++r)
        out[(size_t)(R0 + wr * 64 + mt * 16 + lo * 4 + r) * 512 + n] = acc[mt][nt][r] + bb;
  }
}

extern "C" void kernel_launch(void* const* d_in, const int* in_sizes, int n_in,
                              void* d_out, int out_size, void* d_ws, size_t ws_size,
                              hipStream_t stream) {
  const float* query = (const float*)d_in[0];
  const float* key_a = (const float*)d_in[1];
  const float* val_a = (const float*)d_in[2];
  const float* bias = (const float*)d_in[3];
  const float* Wq = (const float*)d_in[4];
  const float* bq = (const float*)d_in[5];
  const float* Wk = (const float*)d_in[6];
  const float* bk = (const float*)d_in[7];
  const float* Wv = (const float*)d_in[8];
  const float* bv = (const float*)d_in[9];
  const float* Wo = (const float*)d_in[10];
  const float* bo = (const float*)d_in[11];
  float* out = (float*)d_out;
  float* top = out + 16777216;

  short* wt = (short*)d_ws;
  short* qpw = (short*)((char*)d_ws + 2097152);  // x aliases this after attn_mid
  short* kpw = (short*)((char*)d_ws + 35651584);
  short* vpw = (short*)((char*)d_ws + 102760448);

  prep_w<<<1024, 256, 0, stream>>>(Wq, Wk, Wv, Wo, wt);
  proj_all<<<5120, 256, 49152, stream>>>(query, key_a, val_a, bq, bk, bv, wt, qpw, kpw, vpw);
  attn_mid<<<2048, THREADS, 26880, stream>>>(qpw, kpw, vpw, bias, qpw, top);
  out_p<<<1024, 256, 32768, stream>>>(qpw, bo, wt, out);
}